// Round 1
// baseline (211.500 us; speedup 1.0000x reference)
//
#include <hip/hip_runtime.h>

// InjectiveMapping: v[b,p,:] -> 10 layers of (4x4 matmul + bias + leaky_relu)
// with LIFO residual skips; plus per-(l,b) 4x4 determinant broadcast over P.
// L=10, B=16, P=200000, fp32. Memory-bound: ~51 MB read, ~180 MB write.

constexpr int NL = 10;
constexpr int NB = 16;
constexpr int NP = 200000;
constexpr float SLOPE = 0.2f;

__device__ __forceinline__ float lrelu(float x) {
    return x > 0.0f ? x : SLOPE * x;
}

__global__ __launch_bounds__(256) void injective_kernel(
    const float* __restrict__ vertices,   // [B, P, 4]
    const float* __restrict__ weights,    // [L, B, 20]
    float* __restrict__ out_v,            // [B, P, 4]
    float* __restrict__ out_det)          // [L, B, P, 1]
{
    const int b = blockIdx.y;             // block-uniform batch index

    // --- dets for this block's b: 10 threads compute 10 determinants ---
    __shared__ float s_det[NL];
    if (threadIdx.x < NL) {
        const float* m = weights + (threadIdx.x * NB + b) * 20;
        float a00 = m[0],  a01 = m[1],  a02 = m[2],  a03 = m[3];
        float a10 = m[4],  a11 = m[5],  a12 = m[6],  a13 = m[7];
        float a20 = m[8],  a21 = m[9],  a22 = m[10], a23 = m[11];
        float a30 = m[12], a31 = m[13], a32 = m[14], a33 = m[15];
        float s0 = a00 * a11 - a01 * a10;
        float s1 = a00 * a12 - a02 * a10;
        float s2 = a00 * a13 - a03 * a10;
        float s3 = a01 * a12 - a02 * a11;
        float s4 = a01 * a13 - a03 * a11;
        float s5 = a02 * a13 - a03 * a12;
        float c5 = a22 * a33 - a23 * a32;
        float c4 = a21 * a33 - a23 * a31;
        float c3 = a21 * a32 - a22 * a31;
        float c2 = a20 * a33 - a23 * a30;
        float c1 = a20 * a32 - a22 * a30;
        float c0 = a20 * a31 - a21 * a30;
        s_det[threadIdx.x] = s0 * c5 - s1 * c4 + s2 * c3
                           + s3 * c2 - s4 * c1 + s5 * c0;
    }
    __syncthreads();

    const int p = blockIdx.x * blockDim.x + threadIdx.x;
    if (p >= NP) return;
    const int idx = b * NP + p;           // flat point index (fits in int)

    float4 vin = reinterpret_cast<const float4*>(vertices)[idx];
    float x0 = vin.x, x1 = vin.y, x2 = vin.z, x3 = vin.w;

    float res[4][4];                      // residual stack, registers

#pragma unroll
    for (int l = 0; l < NL; ++l) {
        // Uniform address -> compiler emits scalar loads (SGPR weights).
        const float* m = weights + (l * NB + b) * 20;
        // y_e = sum_d x_d * mat[d][e] + bias[e];  mat[d][e] = m[d*4+e]
        float y0 = fmaf(x3, m[12], m[16]);
        float y1 = fmaf(x3, m[13], m[17]);
        float y2 = fmaf(x3, m[14], m[18]);
        float y3 = fmaf(x3, m[15], m[19]);
        y0 = fmaf(x2, m[8],  y0);  y1 = fmaf(x2, m[9],  y1);
        y2 = fmaf(x2, m[10], y2);  y3 = fmaf(x2, m[11], y3);
        y0 = fmaf(x1, m[4],  y0);  y1 = fmaf(x1, m[5],  y1);
        y2 = fmaf(x1, m[6],  y2);  y3 = fmaf(x1, m[7],  y3);
        y0 = fmaf(x0, m[0],  y0);  y1 = fmaf(x0, m[1],  y1);
        y2 = fmaf(x0, m[2],  y2);  y3 = fmaf(x0, m[3],  y3);

        y0 = lrelu(y0); y1 = lrelu(y1); y2 = lrelu(y2); y3 = lrelu(y3);

        if (l < (NL - 1) / 2) {           // l = 0..3: push (post-relu)
            res[l][0] = y0; res[l][1] = y1; res[l][2] = y2; res[l][3] = y3;
        } else if (l > NL / 2) {          // l = 6..9: pop LIFO -> res[9-l]
            const int j = (NL - 1) - l;
            y0 += res[j][0]; y1 += res[j][1];
            y2 += res[j][2]; y3 += res[j][3];
        }
        x0 = y0; x1 = y1; x2 = y2; x3 = y3;
    }

    reinterpret_cast<float4*>(out_v)[idx] = make_float4(x0, x1, x2, x3);

#pragma unroll
    for (int l = 0; l < NL; ++l)
        out_det[l * (NB * NP) + idx] = s_det[l];
}

extern "C" void kernel_launch(void* const* d_in, const int* in_sizes, int n_in,
                              void* d_out, int out_size, void* d_ws, size_t ws_size,
                              hipStream_t stream) {
    const float* vertices = (const float*)d_in[0];   // [16, 200000, 4]
    const float* weights  = (const float*)d_in[1];   // [10, 16, 20]
    float* out_v   = (float*)d_out;                  // first output: v
    float* out_det = (float*)d_out + NB * NP * 4;    // second: det_rep

    dim3 grid((NP + 255) / 256, NB);
    injective_kernel<<<grid, 256, 0, stream>>>(vertices, weights, out_v, out_det);
}